// Round 14
// baseline (376.256 us; speedup 1.0000x reference)
//
#include <hip/hip_runtime.h>
#include <hip/hip_bf16.h>

// ---------------------------------------------------------------------------
// Attention_32100585571137 : round 14
//   - streaming AV: KSPLIT 8 -> 16 (r13: av_fused occupancy-capped at 31%,
//     12 waves/CU, 2.4 TB/s on the S stream). 1536 blocks = 24 waves/CU.
//     av_part_s/psum_s widened to 16 slots (ws fits: ~248 of 268 MB).
// ---------------------------------------------------------------------------

typedef __bf16 bf16;
typedef __attribute__((ext_vector_type(8))) __bf16 bf16x8;
typedef __attribute__((ext_vector_type(4))) __bf16 bf16x4;
typedef __attribute__((ext_vector_type(4))) float f32x4;

#define AS1 __attribute__((address_space(1)))
#define AS3 __attribute__((address_space(3)))

__device__ __forceinline__ void gll16(const void* g, void* l) {
  __builtin_amdgcn_global_load_lds((const AS1 void*)g, (AS3 void*)l, 16, 0, 0);
}

// ------------------------- f32 -> bf16 convert (x4) ------------------------
__global__ void to_bf16_k(const float4* __restrict__ s, bf16x4* __restrict__ d, int n4) {
  int i = blockIdx.x * 256 + threadIdx.x;
  if (i < n4) {
    float4 f = s[i];
    bf16x4 o;
    o[0] = (bf16)f.x; o[1] = (bf16)f.y; o[2] = (bf16)f.z; o[3] = (bf16)f.w;
    d[i] = o;
  }
}

// ------------------------- NT GEMM: C = A * B^T ----------------------------
template<int BM, int BN, int WM, int WN, bool CBF16, bool NCLAMP, bool STATS>
__global__ __launch_bounds__(256, 2)
void gemm_nt(const bf16* __restrict__ A, const bf16* __restrict__ B,
             void* __restrict__ Cp, const float* __restrict__ bias,
             int M, int N, int K, int lda, int ldb, int ldc,
             long sA, long sB, long sC,
             float* __restrict__ pssum, unsigned* __restrict__ psmax, int slotsPerZ)
{
  constexpr int BK = 32;
  constexpr int MF = WM / 16, NF = WN / 16;
  constexpr int NWN = BN / WN;
  __shared__ __align__(16) bf16 As[BM * BK];
  __shared__ __align__(16) bf16 Bs[BN * BK];
  const int tid  = threadIdx.x;
  const int lane = tid & 63;
  const int wid  = tid >> 6;
  const int wm = (wid / NWN) * WM;
  const int wn = (wid % NWN) * WN;
  const int m0 = blockIdx.y * BM;
  const int n0 = blockIdx.x * BN;
  const bf16* Ab = A + (long)blockIdx.z * sA;
  const bf16* Bb = B + (long)blockIdx.z * sB;

  f32x4 acc[MF][NF] = {};
  const int wbase = wid << 10;
  const int aoffb = tid * 16;
  const int qs = ((lane >> 4) ^ ((lane >> 1) & 3)) * 8;

  for (int k0 = 0; k0 < K; k0 += BK) {
    #pragma unroll
    for (int i = 0; i < (BM * BK * 2) / 4096; ++i) {
      int off = i * 4096 + aoffb;
      int row = off >> 6;
      int q   = ((off >> 4) & 3) ^ ((off >> 7) & 3);
      const bf16* g = Ab + (long)(m0 + row) * lda + (k0 + q * 8);
      gll16(g, (char*)As + i * 4096 + wbase);
    }
    #pragma unroll
    for (int i = 0; i < (BN * BK * 2) / 4096; ++i) {
      int off = i * 4096 + aoffb;
      int row = off >> 6;
      int q   = ((off >> 4) & 3) ^ ((off >> 7) & 3);
      int rn = n0 + row;
      if (NCLAMP) rn = (rn < N) ? rn : (N - 1);
      const bf16* g = Bb + (long)rn * ldb + (k0 + q * 8);
      gll16(g, (char*)Bs + i * 4096 + wbase);
    }
    __syncthreads();
    bf16x8 af[MF], bfr[NF];
    #pragma unroll
    for (int i = 0; i < MF; ++i)
      af[i] = *reinterpret_cast<const bf16x8*>(&As[(wm + i * 16 + (lane & 15)) * BK + qs]);
    #pragma unroll
    for (int j = 0; j < NF; ++j)
      bfr[j] = *reinterpret_cast<const bf16x8*>(&Bs[(wn + j * 16 + (lane & 15)) * BK + qs]);
    #pragma unroll
    for (int i = 0; i < MF; ++i)
      #pragma unroll
      for (int j = 0; j < NF; ++j)
        acc[i][j] = __builtin_amdgcn_mfma_f32_16x16x32_bf16(bfr[j], af[i], acc[i][j], 0, 0, 0);
    __syncthreads();
  }

  const long cbase = (long)blockIdx.z * sC;
  if (CBF16) {
    #pragma unroll
    for (int i = 0; i < MF; ++i) {
      const int r = m0 + wm + i * 16 + (lane & 15);
      #pragma unroll
      for (int jh = 0; jh < NF / 2; ++jh) {
        bf16x8 o;
        #pragma unroll
        for (int e = 0; e < 4; ++e) {
          o[e]     = (bf16)acc[i][2 * jh][e];
          o[4 + e] = (bf16)acc[i][2 * jh + 1][e];
        }
        const long idx = cbase + (long)r * ldc + n0 + wn + jh * 32 + ((lane >> 4) << 3);
        *reinterpret_cast<bf16x8*>((bf16*)Cp + idx) = o;
      }
    }
  } else {
    #pragma unroll
    for (int i = 0; i < MF; ++i) {
      const int r = m0 + wm + i * 16 + (lane & 15);
      #pragma unroll
      for (int j = 0; j < NF; ++j) {
        const int c = n0 + wn + j * 16 + ((lane >> 4) << 2);
        if (NCLAMP && c >= N) continue;
        float b0 = 0.0f, b1 = 0.0f, b2 = 0.0f, b3 = 0.0f;
        if (bias) {
          float4 bv = *reinterpret_cast<const float4*>(bias + c);
          b0 = bv.x; b1 = bv.y; b2 = bv.z; b3 = bv.w;
        }
        const long idx = cbase + (long)r * ldc + c;
        *reinterpret_cast<float4*>((float*)Cp + idx) =
            make_float4(acc[i][j][0] + b0, acc[i][j][1] + b1,
                        acc[i][j][2] + b2, acc[i][j][3] + b3);
      }
    }
  }

  if (STATS) {
    const long sbase = ((long)blockIdx.z * slotsPerZ + blockIdx.x * NWN + (wid % NWN)) * M;
    #pragma unroll
    for (int i = 0; i < MF; ++i) {
      float s = 0.0f, mxv = -3.0e38f;
      #pragma unroll
      for (int j = 0; j < NF; ++j)
        #pragma unroll
        for (int rr = 0; rr < 4; ++rr) {
          s += acc[i][j][rr];
          mxv = fmaxf(mxv, acc[i][j][rr]);
        }
      s += __shfl_xor(s, 16, 64);
      s += __shfl_xor(s, 32, 64);
      mxv = fmaxf(mxv, __shfl_xor(mxv, 16, 64));
      mxv = fmaxf(mxv, __shfl_xor(mxv, 32, 64));
      if (lane < 16) {
        const int grow = m0 + wm + i * 16 + lane;
        pssum[sbase + grow] = s;
        unsigned u = __float_as_uint(mxv);
        psmax[sbase + grow] = u ^ (((int)u >> 31) ? 0xFFFFFFFFu : 0x80000000u);
      }
    }
  }
}

// --------------- finalize stats: reduce slots -> (mean, max) ---------------
__global__ void finalize_stats_k(const float* __restrict__ pssum,
                                 const unsigned* __restrict__ psmax,
                                 float4* __restrict__ st,
                                 int nslots, int Mrows, float invL)
{
  const int idx = blockIdx.x * 256 + threadIdx.x;
  const int z = idx / Mrows, r = idx - z * Mrows;
  const float*    ps = pssum + (long)z * nslots * Mrows + r;
  const unsigned* pm = psmax + (long)z * nslots * Mrows + r;
  float s = 0.0f;
  unsigned km = 0;
  for (int i = 0; i < nslots; ++i) {
    s += ps[(long)i * Mrows];
    km = max(km, pm[(long)i * Mrows]);
  }
  unsigned ub = (km & 0x80000000u) ? (km ^ 0x80000000u) : ~km;
  st[idx] = make_float4(s * invL, __uint_as_float(ub), 0.0f, 0.0f);
}

// --------------- split qkv -> q(scaled), k_full, k_m_mod -------------------
__global__ void split_qk_k(const float* __restrict__ qkv, const float* __restrict__ idkv,
                           const float* __restrict__ mem_k,
                           bf16* __restrict__ q_bf, bf16* __restrict__ kfull,
                           bf16* __restrict__ kmm, float* __restrict__ out_kmm)
{
  int idx = blockIdx.x * 256 + threadIdx.x;
  if (idx >= 12 * 5120 * 64) return;
  int d  = idx & 63;
  int hj = idx >> 6;
  int h  = hj / 5120;
  int j  = hj - h * 5120;
  if (j < 2048) {
    kfull[idx] = (bf16)mem_k[((h * 2048 + j) << 6) + d];
  } else {
    int n = j - 2048;
    int base = n * 2304 + (h << 6) + d;
    float qv = qkv[base];
    float kv = qkv[base + 768];
    q_bf[((h * 3072 + n) << 6) + d] = (bf16)(qv * 0.125f);
    kfull[idx] = (bf16)kv;
    if (n < 1024) {
      float m  = 1.0f + tanhf(idkv[n * 780 + h]);
      float km = kv * m;
      int o = ((h * 1024 + n) << 6) + d;
      kmm[o]     = (bf16)km;
      out_kmm[o] = km;
    }
  }
}

// --------------- build v^T (64 x 5120 per head), k-index PI-permuted -------
__global__ void build_vT_k(const float* __restrict__ qkv, const float* __restrict__ idkv,
                           const float* __restrict__ mem_v,
                           bf16* __restrict__ vT, float* __restrict__ out_vm)
{
  __shared__ float tile[64][65];
  int h  = blockIdx.y;
  int j0 = blockIdx.x << 6;
  int tid = threadIdx.x;
  #pragma unroll
  for (int i = 0; i < 16; ++i) {
    int el = i * 256 + tid;
    int jj = el >> 6, d = el & 63;
    int j = j0 + jj;
    float v;
    if (j < 2048) {
      v = mem_v[((h * 2048 + j) << 6) + d];
    } else {
      int n = j - 2048;
      v = qkv[n * 2304 + 1536 + (h << 6) + d];
      if (n < 1024) {
        v += idkv[n * 780 + 12 + (h << 6) + d];
        out_vm[((h * 1024 + n) << 6) + d] = v;
      }
    }
    tile[jj][d] = v;
  }
  __syncthreads();
  #pragma unroll
  for (int i = 0; i < 16; ++i) {
    int el = i * 256 + tid;
    int d = el >> 6, jj = el & 63;
    int pos = (jj & 32) + (((jj >> 2) & 3) << 3) + (((jj >> 4) & 1) << 2) + (jj & 3);
    vT[((long)(h * 64 + d)) * 5120 + j0 + pos] = (bf16)tile[jj][d];
  }
}

// --------------- fused AV: LDS dbuf B + swizzle, A prefetch ----------------
template<int KSPLIT>
__global__ __launch_bounds__(256)
void av_fused(const bf16* __restrict__ S, const float4* __restrict__ st,
              const bf16* __restrict__ vT, float* __restrict__ part,
              float* __restrict__ psum, int Mrows, int L, int vT_off, int h0)
{
  __shared__ __align__(16) bf16 Bs[2][64 * 32];
  const int tid = threadIdx.x, lane = tid & 63, w = tid >> 6;
  const int hl = blockIdx.y;
  const int h  = h0 + hl;
  const int i0 = blockIdx.x * 64;
  const int kchunk = L / KSPLIT;
  const int kbase = blockIdx.z * kchunk;
  const int nsteps = kchunk / 32;

  const bf16* vTh = vT + (long)h * 64 * 5120 + vT_off;
  const int srow = tid >> 2;
  const int ssub = (tid & 3) ^ ((tid >> 3) & 3);
  const bf16* bsrc = vTh + (long)srow * 5120 + kbase + ssub * 8;

  const int arow = i0 + w * 16 + (lane & 15);
  const bf16* ap = S + ((long)hl * Mrows + arow) * L + kbase + ((lane >> 4) * 8);
  const float4 s4 = st[h * Mrows + arow];
  const float t = s4.x, mx = s4.y;

  const int rb0 = lane & 15;
  const int k0s = ((lane >> 4) ^ ((lane >> 1) & 3)) * 16;

  f32x4 acc[4] = {};
  float lsum = 0.0f;
  gll16(bsrc, (char*)Bs[0] + tid * 16);
  bf16x8 a8 = *reinterpret_cast<const bf16x8*>(ap);
  __syncthreads();

  for (int s = 0; s < nsteps; ++s) {
    if (s + 1 < nsteps) gll16(bsrc + (s + 1) * 32, (char*)Bs[(s + 1) & 1] + tid * 16);
    bf16x8 a_nxt = (s + 1 < nsteps) ? *reinterpret_cast<const bf16x8*>(ap + (s + 1) * 32) : a8;
    bf16x8 af;
    #pragma unroll
    for (int e = 0; e < 8; ++e) {
      float v = (float)a8[e];
      float pv = (v >= t) ? __expf(v - mx) : 0.0f;
      af[e] = (bf16)pv;
      lsum += pv;
    }
    const char* bb = (const char*)Bs[s & 1];
    #pragma unroll
    for (int j = 0; j < 4; ++j) {
      bf16x8 b8 = *reinterpret_cast<const bf16x8*>(bb + (j * 16 + rb0) * 64 + k0s);
      acc[j] = __builtin_amdgcn_mfma_f32_16x16x32_bf16(af, b8, acc[j], 0, 0, 0);
    }
    __syncthreads();
    a8 = a_nxt;
  }

  lsum += __shfl_down(lsum, 32, 64);
  lsum += __shfl_down(lsum, 16, 64);
  if ((lane >> 4) == 0)
    psum[((long)blockIdx.z * 12 + h) * Mrows + arow] = lsum;

  float* pp = part + (long)blockIdx.z * Mrows * 768;
  const int rb = i0 + w * 16 + ((lane >> 4) << 2);
  #pragma unroll
  for (int j = 0; j < 4; ++j) {
    const int c = h * 64 + j * 16 + (lane & 15);
    #pragma unroll
    for (int r = 0; r < 4; ++r)
      pp[(long)(rb + r) * 768 + c] = acc[j][r];
  }
}

// --------------- reduce split-K partials, normalize, cvt bf16 --------------
__global__ void reduce_cvt_k(const float4* __restrict__ part_m, const float4* __restrict__ part_s,
                             bf16x4* __restrict__ xatt,
                             const float* __restrict__ psum_m, const float* __restrict__ psum_s)
{
  const int idx = blockIdx.x * 256 + threadIdx.x;
  if (idx >= 589824) return;
  const int row = idx / 192;
  const int c4 = idx - row * 192;
  const int h = (c4 * 4) >> 6;
  float sx, sy, sz, sw, sum;
  if (row < 1024) {
    constexpr long P4 = (long)1024 * 192;
    float4 a = part_m[(long)row * 192 + c4];
    float4 b = part_m[P4 + (long)row * 192 + c4];
    sx = a.x + b.x; sy = a.y + b.y; sz = a.z + b.z; sw = a.w + b.w;
    sum = psum_m[h * 1024 + row] + psum_m[12 * 1024 + h * 1024 + row];
  } else {
    const int r = row - 1024;
    constexpr long P4 = (long)2048 * 192;
    sx = sy = sz = sw = 0.0f;
    sum = 0.0f;
    #pragma unroll
    for (int z = 0; z < 16; ++z) {
      float4 a = part_s[(long)z * P4 + (long)r * 192 + c4];
      sx += a.x; sy += a.y; sz += a.z; sw += a.w;
      sum += psum_s[((long)z * 12 + h) * 2048 + r];
    }
  }
  const float inv = 1.0f / sum;
  bf16x4 o;
  o[0] = (bf16)(sx * inv); o[1] = (bf16)(sy * inv);
  o[2] = (bf16)(sz * inv); o[3] = (bf16)(sw * inv);
  xatt[idx] = o;
}

// ---------------------------------------------------------------------------
extern "C" void kernel_launch(void* const* d_in, const int* in_sizes, int n_in,
                              void* d_out, int out_size, void* d_ws, size_t ws_size,
                              hipStream_t stream)
{
  (void)in_sizes; (void)n_in; (void)out_size;
  const float* x      = (const float*)d_in[0];
  const float* id_tot = (const float*)d_in[1];
  const float* mem_k  = (const float*)d_in[2];
  const float* mem_v  = (const float*)d_in[3];
  const float* w_qkv  = (const float*)d_in[4];
  const float* w_idkv = (const float*)d_in[5];
  const float* b_idkv = (const float*)d_in[6];
  const float* w_proj = (const float*)d_in[7];
  const float* b_proj = (const float*)d_in[8];

  float* out     = (float*)d_out;
  float* out_kmm = out + (size_t)3072 * 768;
  float* out_vm  = out_kmm + (size_t)12 * 1024 * 64;

  char* cur = (char*)d_ws;
  auto sub = [&](size_t b) { char* p = cur; cur += (b + 255) & ~(size_t)255; return p; };

  // ---- union region: early temps (dead after split/build) vs av_part_s ----
  char* uni0 = cur;
  bf16*  x_bf     = (bf16*) sub((size_t)3072 * 768 * 2);
  bf16*  wqkv_bf  = (bf16*) sub((size_t)2304 * 768 * 2);
  bf16*  id_bf    = (bf16*) sub((size_t)1024 * 768 * 2);
  bf16*  widkv_bf = (bf16*) sub((size_t)780 * 768 * 2);
  float* qkv_f    = (float*)sub((size_t)3072 * 2304 * 4);
  float* idkv_f   = (float*)sub((size_t)1024 * 780 * 4);
  char* uniEndA = cur;
  float* av_part_s = (float*)uni0;                      // 16 * 2048*768 f32
  char* uniEndB = uni0 + (size_t)16 * 2048 * 768 * 4;
  cur = (uniEndA > uniEndB) ? uniEndA : uniEndB;

  // ---- persistent ----
  bf16*     wproj_bf  = (bf16*)    sub((size_t)768 * 768 * 2);
  bf16*     q_bf      = (bf16*)    sub((size_t)12 * 3072 * 64 * 2);
  bf16*     kfull_bf  = (bf16*)    sub((size_t)12 * 5120 * 64 * 2);
  bf16*     vT_bf     = (bf16*)    sub((size_t)12 * 64 * 5120 * 2);
  bf16*     kmm_bf    = (bf16*)    sub((size_t)12 * 1024 * 64 * 2);
  bf16*     S_m       = (bf16*)    sub((size_t)12 * 1024 * 1024 * 2);
  float*    av_part_m = (float*)   sub((size_t)2 * 1024 * 768 * 4);
  float4*   stats_m   = (float4*)  sub((size_t)12 * 1024 * 16);
  float4*   stats_s   = (float4*)  sub((size_t)12 * 2048 * 16);
  float*    psum_m    = (float*)   sub((size_t)2 * 12 * 1024 * 4);
  float*    psum_s    = (float*)   sub((size_t)16 * 12 * 2048 * 4);
  float*    pss_m     = (float*)   sub((size_t)12 * 16 * 1024 * 4);
  unsigned* psm_m     = (unsigned*)sub((size_t)12 * 16 * 1024 * 4);
  float*    pss_s     = (float*)   sub((size_t)12 * 80 * 2048 * 4);
  unsigned* psm_s     = (unsigned*)sub((size_t)12 * 80 * 2048 * 4);
  bf16*     xatt_bf   = (bf16*)    sub((size_t)3072 * 768 * 2);
  size_t fixed = (size_t)(cur - (char*)d_ws);

  int CH = 1;
  const int chs[6] = {12, 6, 4, 3, 2, 1};
  for (int i = 0; i < 6; ++i) {
    if (fixed + (size_t)chs[i] * 2048 * 5120 * 2 + 256 <= ws_size) { CH = chs[i]; break; }
  }
  if (fixed + (size_t)CH * 2048 * 5120 * 2 + 256 > ws_size) return;
  bf16* S_s = (bf16*)sub((size_t)CH * 2048 * 5120 * 2);

  // --- bf16 conversions ---
  to_bf16_k<<<2304, 256, 0, stream>>>((const float4*)x,      (bf16x4*)x_bf,     589824);
  to_bf16_k<<<1728, 256, 0, stream>>>((const float4*)w_qkv,  (bf16x4*)wqkv_bf,  442368);
  to_bf16_k<<< 768, 256, 0, stream>>>((const float4*)id_tot, (bf16x4*)id_bf,    196608);
  to_bf16_k<<< 585, 256, 0, stream>>>((const float4*)w_idkv, (bf16x4*)widkv_bf, 149760);
  to_bf16_k<<< 576, 256, 0, stream>>>((const float4*)w_proj, (bf16x4*)wproj_bf, 147456);

  // --- projections (no stats) ---
  gemm_nt<128,128,64,64,false,false,false><<<dim3(18, 24, 1), 256, 0, stream>>>(
      x_bf, wqkv_bf, qkv_f, nullptr, 3072, 2304, 768, 768, 768, 2304, 0, 0, 0,
      nullptr, nullptr, 0);
  gemm_nt<128,128,64,64,false,true,false><<<dim3(7, 8, 1), 256, 0, stream>>>(
      id_bf, widkv_bf, idkv_f, b_idkv, 1024, 780, 768, 768, 768, 780, 0, 0, 0,
      nullptr, nullptr, 0);

  // --- split + modulate + transposes ---
  split_qk_k<<<15360, 256, 0, stream>>>(qkv_f, idkv_f, mem_k, q_bf, kfull_bf, kmm_bf, out_kmm);
  build_vT_k<<<dim3(80, 12, 1), 256, 0, stream>>>(qkv_f, idkv_f, mem_v, vT_bf, out_vm);

  // --- memory-branch attention (L=1024) ---
  gemm_nt<128,128,64,64,true,false,true><<<dim3(8, 8, 12), 256, 0, stream>>>(
      q_bf, kmm_bf, S_m, nullptr, 1024, 1024, 64, 64, 64, 1024,
      (long)3072 * 64, (long)1024 * 64, (long)1024 * 1024, pss_m, psm_m, 16);
  finalize_stats_k<<<48, 256, 0, stream>>>(pss_m, psm_m, stats_m, 16, 1024, 1.0f / 1024.0f);
  av_fused<2><<<dim3(16, 12, 2), 256, 0, stream>>>(
      S_m, stats_m, vT_bf, av_part_m, psum_m, 1024, 1024, 2048, 0);

  // --- streaming-branch attention (L=5120), chunked over heads ---
  for (int h0 = 0; h0 < 12; h0 += CH) {
    gemm_nt<128,128,64,64,true,false,true><<<dim3(40, 16, CH), 256, 0, stream>>>(
        q_bf + (size_t)h0 * 3072 * 64 + 1024 * 64, kfull_bf + (size_t)h0 * 5120 * 64,
        S_s, nullptr, 2048, 5120, 64, 64, 64, 5120,
        (long)3072 * 64, (long)5120 * 64, (long)2048 * 5120, pss_s, psm_s, 80);
    finalize_stats_k<<<CH * 8, 256, 0, stream>>>(
        pss_s, psm_s, stats_s + (size_t)h0 * 2048, 80, 2048, 1.0f / 5120.0f);
    av_fused<16><<<dim3(32, CH, 16), 256, 0, stream>>>(
        S_s, stats_s, vT_bf, av_part_s, psum_s, 2048, 5120, 0, h0);
  }

  // --- reduce partials (normalize) + output projection ---
  reduce_cvt_k<<<2304, 256, 0, stream>>>((const float4*)av_part_m, (const float4*)av_part_s,
                                         (bf16x4*)xatt_bf, psum_m, psum_s);
  gemm_nt<128,128,64,64,false,false,false><<<dim3(6, 24, 1), 256, 0, stream>>>(
      xatt_bf, wproj_bf, out, b_proj, 3072, 768, 768, 768, 768, 768, 0, 0, 0,
      nullptr, nullptr, 0);
}

// Round 15
// 327.224 us; speedup vs baseline: 1.1498x; 1.1498x over previous
//
#include <hip/hip_runtime.h>
#include <hip/hip_bf16.h>

// ---------------------------------------------------------------------------
// Attention_32100585571137 : round 15
//   - REVERT r14 (KSPLIT back to 8, 8 partial slots, CH=6 restored).
//   - av_fused: 64 columns per barrier (was 32): 16KB dbuf B tile, 2 gll16 +
//     2 A-prefetch + 16 exp + 8 MFMA per step -> 10 barriers instead of 20,
//     2x work per vmcnt(0) drain. LDS swizzle re-derived for 128B rows:
//     slot' = slot ^ (row&7) (linear gll16 dest + inv-swz source + swz read).
// ---------------------------------------------------------------------------

typedef __bf16 bf16;
typedef __attribute__((ext_vector_type(8))) __bf16 bf16x8;
typedef __attribute__((ext_vector_type(4))) __bf16 bf16x4;
typedef __attribute__((ext_vector_type(4))) float f32x4;

#define AS1 __attribute__((address_space(1)))
#define AS3 __attribute__((address_space(3)))

__device__ __forceinline__ void gll16(const void* g, void* l) {
  __builtin_amdgcn_global_load_lds((const AS1 void*)g, (AS3 void*)l, 16, 0, 0);
}

// ------------------------- f32 -> bf16 convert (x4) ------------------------
__global__ void to_bf16_k(const float4* __restrict__ s, bf16x4* __restrict__ d, int n4) {
  int i = blockIdx.x * 256 + threadIdx.x;
  if (i < n4) {
    float4 f = s[i];
    bf16x4 o;
    o[0] = (bf16)f.x; o[1] = (bf16)f.y; o[2] = (bf16)f.z; o[3] = (bf16)f.w;
    d[i] = o;
  }
}

// ------------------------- NT GEMM: C = A * B^T ----------------------------
template<int BM, int BN, int WM, int WN, bool CBF16, bool NCLAMP, bool STATS>
__global__ __launch_bounds__(256, 2)
void gemm_nt(const bf16* __restrict__ A, const bf16* __restrict__ B,
             void* __restrict__ Cp, const float* __restrict__ bias,
             int M, int N, int K, int lda, int ldb, int ldc,
             long sA, long sB, long sC,
             float* __restrict__ pssum, unsigned* __restrict__ psmax, int slotsPerZ)
{
  constexpr int BK = 32;
  constexpr int MF = WM / 16, NF = WN / 16;
  constexpr int NWN = BN / WN;
  __shared__ __align__(16) bf16 As[BM * BK];
  __shared__ __align__(16) bf16 Bs[BN * BK];
  const int tid  = threadIdx.x;
  const int lane = tid & 63;
  const int wid  = tid >> 6;
  const int wm = (wid / NWN) * WM;
  const int wn = (wid % NWN) * WN;
  const int m0 = blockIdx.y * BM;
  const int n0 = blockIdx.x * BN;
  const bf16* Ab = A + (long)blockIdx.z * sA;
  const bf16* Bb = B + (long)blockIdx.z * sB;

  f32x4 acc[MF][NF] = {};
  const int wbase = wid << 10;
  const int aoffb = tid * 16;
  const int qs = ((lane >> 4) ^ ((lane >> 1) & 3)) * 8;

  for (int k0 = 0; k0 < K; k0 += BK) {
    #pragma unroll
    for (int i = 0; i < (BM * BK * 2) / 4096; ++i) {
      int off = i * 4096 + aoffb;
      int row = off >> 6;
      int q   = ((off >> 4) & 3) ^ ((off >> 7) & 3);
      const bf16* g = Ab + (long)(m0 + row) * lda + (k0 + q * 8);
      gll16(g, (char*)As + i * 4096 + wbase);
    }
    #pragma unroll
    for (int i = 0; i < (BN * BK * 2) / 4096; ++i) {
      int off = i * 4096 + aoffb;
      int row = off >> 6;
      int q   = ((off >> 4) & 3) ^ ((off >> 7) & 3);
      int rn = n0 + row;
      if (NCLAMP) rn = (rn < N) ? rn : (N - 1);
      const bf16* g = Bb + (long)rn * ldb + (k0 + q * 8);
      gll16(g, (char*)Bs + i * 4096 + wbase);
    }
    __syncthreads();
    bf16x8 af[MF], bfr[NF];
    #pragma unroll
    for (int i = 0; i < MF; ++i)
      af[i] = *reinterpret_cast<const bf16x8*>(&As[(wm + i * 16 + (lane & 15)) * BK + qs]);
    #pragma unroll
    for (int j = 0; j < NF; ++j)
      bfr[j] = *reinterpret_cast<const bf16x8*>(&Bs[(wn + j * 16 + (lane & 15)) * BK + qs]);
    #pragma unroll
    for (int i = 0; i < MF; ++i)
      #pragma unroll
      for (int j = 0; j < NF; ++j)
        acc[i][j] = __builtin_amdgcn_mfma_f32_16x16x32_bf16(bfr[j], af[i], acc[i][j], 0, 0, 0);
    __syncthreads();
  }

  const long cbase = (long)blockIdx.z * sC;
  if (CBF16) {
    #pragma unroll
    for (int i = 0; i < MF; ++i) {
      const int r = m0 + wm + i * 16 + (lane & 15);
      #pragma unroll
      for (int jh = 0; jh < NF / 2; ++jh) {
        bf16x8 o;
        #pragma unroll
        for (int e = 0; e < 4; ++e) {
          o[e]     = (bf16)acc[i][2 * jh][e];
          o[4 + e] = (bf16)acc[i][2 * jh + 1][e];
        }
        const long idx = cbase + (long)r * ldc + n0 + wn + jh * 32 + ((lane >> 4) << 3);
        *reinterpret_cast<bf16x8*>((bf16*)Cp + idx) = o;
      }
    }
  } else {
    #pragma unroll
    for (int i = 0; i < MF; ++i) {
      const int r = m0 + wm + i * 16 + (lane & 15);
      #pragma unroll
      for (int j = 0; j < NF; ++j) {
        const int c = n0 + wn + j * 16 + ((lane >> 4) << 2);
        if (NCLAMP && c >= N) continue;
        float b0 = 0.0f, b1 = 0.0f, b2 = 0.0f, b3 = 0.0f;
        if (bias) {
          float4 bv = *reinterpret_cast<const float4*>(bias + c);
          b0 = bv.x; b1 = bv.y; b2 = bv.z; b3 = bv.w;
        }
        const long idx = cbase + (long)r * ldc + c;
        *reinterpret_cast<float4*>((float*)Cp + idx) =
            make_float4(acc[i][j][0] + b0, acc[i][j][1] + b1,
                        acc[i][j][2] + b2, acc[i][j][3] + b3);
      }
    }
  }

  if (STATS) {
    const long sbase = ((long)blockIdx.z * slotsPerZ + blockIdx.x * NWN + (wid % NWN)) * M;
    #pragma unroll
    for (int i = 0; i < MF; ++i) {
      float s = 0.0f, mxv = -3.0e38f;
      #pragma unroll
      for (int j = 0; j < NF; ++j)
        #pragma unroll
        for (int rr = 0; rr < 4; ++rr) {
          s += acc[i][j][rr];
          mxv = fmaxf(mxv, acc[i][j][rr]);
        }
      s += __shfl_xor(s, 16, 64);
      s += __shfl_xor(s, 32, 64);
      mxv = fmaxf(mxv, __shfl_xor(mxv, 16, 64));
      mxv = fmaxf(mxv, __shfl_xor(mxv, 32, 64));
      if (lane < 16) {
        const int grow = m0 + wm + i * 16 + lane;
        pssum[sbase + grow] = s;
        unsigned u = __float_as_uint(mxv);
        psmax[sbase + grow] = u ^ (((int)u >> 31) ? 0xFFFFFFFFu : 0x80000000u);
      }
    }
  }
}

// --------------- finalize stats: reduce slots -> (mean, max) ---------------
__global__ void finalize_stats_k(const float* __restrict__ pssum,
                                 const unsigned* __restrict__ psmax,
                                 float4* __restrict__ st,
                                 int nslots, int Mrows, float invL)
{
  const int idx = blockIdx.x * 256 + threadIdx.x;
  const int z = idx / Mrows, r = idx - z * Mrows;
  const float*    ps = pssum + (long)z * nslots * Mrows + r;
  const unsigned* pm = psmax + (long)z * nslots * Mrows + r;
  float s = 0.0f;
  unsigned km = 0;
  for (int i = 0; i < nslots; ++i) {
    s += ps[(long)i * Mrows];
    km = max(km, pm[(long)i * Mrows]);
  }
  unsigned ub = (km & 0x80000000u) ? (km ^ 0x80000000u) : ~km;
  st[idx] = make_float4(s * invL, __uint_as_float(ub), 0.0f, 0.0f);
}

// --------------- split qkv -> q(scaled), k_full, k_m_mod -------------------
__global__ void split_qk_k(const float* __restrict__ qkv, const float* __restrict__ idkv,
                           const float* __restrict__ mem_k,
                           bf16* __restrict__ q_bf, bf16* __restrict__ kfull,
                           bf16* __restrict__ kmm, float* __restrict__ out_kmm)
{
  int idx = blockIdx.x * 256 + threadIdx.x;
  if (idx >= 12 * 5120 * 64) return;
  int d  = idx & 63;
  int hj = idx >> 6;
  int h  = hj / 5120;
  int j  = hj - h * 5120;
  if (j < 2048) {
    kfull[idx] = (bf16)mem_k[((h * 2048 + j) << 6) + d];
  } else {
    int n = j - 2048;
    int base = n * 2304 + (h << 6) + d;
    float qv = qkv[base];
    float kv = qkv[base + 768];
    q_bf[((h * 3072 + n) << 6) + d] = (bf16)(qv * 0.125f);
    kfull[idx] = (bf16)kv;
    if (n < 1024) {
      float m  = 1.0f + tanhf(idkv[n * 780 + h]);
      float km = kv * m;
      int o = ((h * 1024 + n) << 6) + d;
      kmm[o]     = (bf16)km;
      out_kmm[o] = km;
    }
  }
}

// --------------- build v^T (64 x 5120 per head), k-index PI-permuted -------
__global__ void build_vT_k(const float* __restrict__ qkv, const float* __restrict__ idkv,
                           const float* __restrict__ mem_v,
                           bf16* __restrict__ vT, float* __restrict__ out_vm)
{
  __shared__ float tile[64][65];
  int h  = blockIdx.y;
  int j0 = blockIdx.x << 6;
  int tid = threadIdx.x;
  #pragma unroll
  for (int i = 0; i < 16; ++i) {
    int el = i * 256 + tid;
    int jj = el >> 6, d = el & 63;
    int j = j0 + jj;
    float v;
    if (j < 2048) {
      v = mem_v[((h * 2048 + j) << 6) + d];
    } else {
      int n = j - 2048;
      v = qkv[n * 2304 + 1536 + (h << 6) + d];
      if (n < 1024) {
        v += idkv[n * 780 + 12 + (h << 6) + d];
        out_vm[((h * 1024 + n) << 6) + d] = v;
      }
    }
    tile[jj][d] = v;
  }
  __syncthreads();
  #pragma unroll
  for (int i = 0; i < 16; ++i) {
    int el = i * 256 + tid;
    int d = el >> 6, jj = el & 63;
    int pos = (jj & 32) + (((jj >> 2) & 3) << 3) + (((jj >> 4) & 1) << 2) + (jj & 3);
    vT[((long)(h * 64 + d)) * 5120 + j0 + pos] = (bf16)tile[jj][d];
  }
}

// --------------- fused AV: 64-col steps, LDS dbuf B, swizzled --------------
// block = 64 rows x 64 d-cols of one K-chunk; per step: 64x64 B tile staged
// (2 gll16/wave), 2 A vectors prefetched, 16 exp + 8 MFMA, ONE barrier.
// LDS [64 rows][8 slots of 16B], slot' = slot ^ (row&7): bank = f(slot) only
// -> 16-lane fragment read covers all 32 banks (2-way, free).
template<int KSPLIT>
__global__ __launch_bounds__(256)
void av_fused(const bf16* __restrict__ S, const float4* __restrict__ st,
              const bf16* __restrict__ vT, float* __restrict__ part,
              float* __restrict__ psum, int Mrows, int L, int vT_off, int h0)
{
  __shared__ __align__(16) bf16 Bs[2][64 * 64];
  const int tid = threadIdx.x, lane = tid & 63, w = tid >> 6;
  const int hl = blockIdx.y;
  const int h  = h0 + hl;
  const int i0 = blockIdx.x * 64;
  const int kchunk = L / KSPLIT;
  const int kbase = blockIdx.z * kchunk;
  const int nst = kchunk / 64;

  // staging: pass p (0,1) covers rows p*32 + w*8 + (lane>>3); slot qi=lane&7;
  // source slot inverse-swizzled: qi ^ (row & 7)
  const bf16* vTh = vT + (long)h * 64 * 5120 + vT_off;
  const int r0s = w * 8 + (lane >> 3);
  const int r1s = 32 + r0s;
  const int qi  = lane & 7;
  const bf16* bsrc0 = vTh + (long)r0s * 5120 + kbase + (qi ^ (r0s & 7)) * 8;
  const bf16* bsrc1 = vTh + (long)r1s * 5120 + kbase + (qi ^ (r1s & 7)) * 8;

  const int arow = i0 + w * 16 + (lane & 15);
  const bf16* ap = S + ((long)hl * Mrows + arow) * L + kbase + ((lane >> 4) * 8);
  const float4 s4 = st[h * Mrows + arow];
  const float t = s4.x, mx = s4.y;

  const int rb0 = lane & 15;
  const int g0 = lane >> 4;           // k-slot for first 32 cols
  const int g1 = g0 + 4;              // k-slot for second 32 cols

  f32x4 acc[4] = {};
  float lsum = 0.0f;
  gll16(bsrc0, (char*)Bs[0] + w * 1024 + lane * 16);
  gll16(bsrc1, (char*)Bs[0] + 4096 + w * 1024 + lane * 16);
  bf16x8 a0 = *reinterpret_cast<const bf16x8*>(ap);
  bf16x8 a1 = *reinterpret_cast<const bf16x8*>(ap + 32);
  __syncthreads();

  for (int s = 0; s < nst; ++s) {
    if (s + 1 < nst) {
      gll16(bsrc0 + (s + 1) * 64, (char*)Bs[(s + 1) & 1] + w * 1024 + lane * 16);
      gll16(bsrc1 + (s + 1) * 64, (char*)Bs[(s + 1) & 1] + 4096 + w * 1024 + lane * 16);
    }
    bf16x8 a0n = (s + 1 < nst) ? *reinterpret_cast<const bf16x8*>(ap + (s + 1) * 64) : a0;
    bf16x8 a1n = (s + 1 < nst) ? *reinterpret_cast<const bf16x8*>(ap + (s + 1) * 64 + 32) : a1;
    bf16x8 af0, af1;
    #pragma unroll
    for (int e = 0; e < 8; ++e) {
      float v0 = (float)a0[e];
      float p0 = (v0 >= t) ? __expf(v0 - mx) : 0.0f;
      af0[e] = (bf16)p0;
      lsum += p0;
      float v1 = (float)a1[e];
      float p1 = (v1 >= t) ? __expf(v1 - mx) : 0.0f;
      af1[e] = (bf16)p1;
      lsum += p1;
    }
    const char* bb = (const char*)Bs[s & 1];
    #pragma unroll
    for (int j = 0; j < 4; ++j) {
      const int row = j * 16 + rb0;
      bf16x8 b80 = *reinterpret_cast<const bf16x8*>(bb + row * 128 + ((g0 ^ (row & 7)) << 4));
      bf16x8 b81 = *reinterpret_cast<const bf16x8*>(bb + row * 128 + ((g1 ^ (row & 7)) << 4));
      acc[j] = __builtin_amdgcn_mfma_f32_16x16x32_bf16(af0, b80, acc[j], 0, 0, 0);
      acc[j] = __builtin_amdgcn_mfma_f32_16x16x32_bf16(af1, b81, acc[j], 0, 0, 0);
    }
    __syncthreads();
    a0 = a0n;
    a1 = a1n;
  }

  lsum += __shfl_down(lsum, 32, 64);
  lsum += __shfl_down(lsum, 16, 64);
  if ((lane >> 4) == 0)
    psum[((long)blockIdx.z * 12 + h) * Mrows + arow] = lsum;

  float* pp = part + (long)blockIdx.z * Mrows * 768;
  const int rb = i0 + w * 16 + ((lane >> 4) << 2);
  #pragma unroll
  for (int j = 0; j < 4; ++j) {
    const int c = h * 64 + j * 16 + (lane & 15);
    #pragma unroll
    for (int r = 0; r < 4; ++r)
      pp[(long)(rb + r) * 768 + c] = acc[j][r];
  }
}

// --------------- reduce split-K partials, normalize, cvt bf16 --------------
__global__ void reduce_cvt_k(const float4* __restrict__ part_m, const float4* __restrict__ part_s,
                             bf16x4* __restrict__ xatt,
                             const float* __restrict__ psum_m, const float* __restrict__ psum_s)
{
  const int idx = blockIdx.x * 256 + threadIdx.x;
  if (idx >= 589824) return;
  const int row = idx / 192;
  const int c4 = idx - row * 192;
  const int h = (c4 * 4) >> 6;
  float sx, sy, sz, sw, sum;
  if (row < 1024) {
    constexpr long P4 = (long)1024 * 192;
    float4 a = part_m[(long)row * 192 + c4];
    float4 b = part_m[P4 + (long)row * 192 + c4];
    sx = a.x + b.x; sy = a.y + b.y; sz = a.z + b.z; sw = a.w + b.w;
    sum = psum_m[h * 1024 + row] + psum_m[12 * 1024 + h * 1024 + row];
  } else {
    const int r = row - 1024;
    constexpr long P4 = (long)2048 * 192;
    sx = sy = sz = sw = 0.0f;
    sum = 0.0f;
    #pragma unroll
    for (int z = 0; z < 8; ++z) {
      float4 a = part_s[(long)z * P4 + (long)r * 192 + c4];
      sx += a.x; sy += a.y; sz += a.z; sw += a.w;
      sum += psum_s[((long)z * 12 + h) * 2048 + r];
    }
  }
  const float inv = 1.0f / sum;
  bf16x4 o;
  o[0] = (bf16)(sx * inv); o[1] = (bf16)(sy * inv);
  o[2] = (bf16)(sz * inv); o[3] = (bf16)(sw * inv);
  xatt[idx] = o;
}

// ---------------------------------------------------------------------------
extern "C" void kernel_launch(void* const* d_in, const int* in_sizes, int n_in,
                              void* d_out, int out_size, void* d_ws, size_t ws_size,
                              hipStream_t stream)
{
  (void)in_sizes; (void)n_in; (void)out_size;
  const float* x      = (const float*)d_in[0];
  const float* id_tot = (const float*)d_in[1];
  const float* mem_k  = (const float*)d_in[2];
  const float* mem_v  = (const float*)d_in[3];
  const float* w_qkv  = (const float*)d_in[4];
  const float* w_idkv = (const float*)d_in[5];
  const float* b_idkv = (const float*)d_in[6];
  const float* w_proj = (const float*)d_in[7];
  const float* b_proj = (const float*)d_in[8];

  float* out     = (float*)d_out;
  float* out_kmm = out + (size_t)3072 * 768;
  float* out_vm  = out_kmm + (size_t)12 * 1024 * 64;

  char* cur = (char*)d_ws;
  auto sub = [&](size_t b) { char* p = cur; cur += (b + 255) & ~(size_t)255; return p; };

  // ---- union region: early temps (dead after split/build) vs av_part_s ----
  char* uni0 = cur;
  bf16*  x_bf     = (bf16*) sub((size_t)3072 * 768 * 2);
  bf16*  wqkv_bf  = (bf16*) sub((size_t)2304 * 768 * 2);
  bf16*  id_bf    = (bf16*) sub((size_t)1024 * 768 * 2);
  bf16*  widkv_bf = (bf16*) sub((size_t)780 * 768 * 2);
  float* qkv_f    = (float*)sub((size_t)3072 * 2304 * 4);
  float* idkv_f   = (float*)sub((size_t)1024 * 780 * 4);
  char* uniEndA = cur;
  float* av_part_s = (float*)uni0;                      // 8 * 2048*768 f32
  char* uniEndB = uni0 + (size_t)8 * 2048 * 768 * 4;
  cur = (uniEndA > uniEndB) ? uniEndA : uniEndB;

  // ---- persistent ----
  bf16*     wproj_bf  = (bf16*)    sub((size_t)768 * 768 * 2);
  bf16*     q_bf      = (bf16*)    sub((size_t)12 * 3072 * 64 * 2);
  bf16*     kfull_bf  = (bf16*)    sub((size_t)12 * 5120 * 64 * 2);
  bf16*     vT_bf     = (bf16*)    sub((size_t)12 * 64 * 5120 * 2);
  bf16*     kmm_bf    = (bf16*)    sub((size_t)12 * 1024 * 64 * 2);
  bf16*     S_m       = (bf16*)    sub((size_t)12 * 1024 * 1024 * 2);
  float*    av_part_m = (float*)   sub((size_t)2 * 1024 * 768 * 4);
  float4*   stats_m   = (float4*)  sub((size_t)12 * 1024 * 16);
  float4*   stats_s   = (float4*)  sub((size_t)12 * 2048 * 16);
  float*    psum_m    = (float*)   sub((size_t)2 * 12 * 1024 * 4);
  float*    psum_s    = (float*)   sub((size_t)8 * 12 * 2048 * 4);
  float*    pss_m     = (float*)   sub((size_t)12 * 16 * 1024 * 4);
  unsigned* psm_m     = (unsigned*)sub((size_t)12 * 16 * 1024 * 4);
  float*    pss_s     = (float*)   sub((size_t)12 * 80 * 2048 * 4);
  unsigned* psm_s     = (unsigned*)sub((size_t)12 * 80 * 2048 * 4);
  bf16*     xatt_bf   = (bf16*)    sub((size_t)3072 * 768 * 2);
  size_t fixed = (size_t)(cur - (char*)d_ws);

  int CH = 1;
  const int chs[6] = {12, 6, 4, 3, 2, 1};
  for (int i = 0; i < 6; ++i) {
    if (fixed + (size_t)chs[i] * 2048 * 5120 * 2 + 256 <= ws_size) { CH = chs[i]; break; }
  }
  if (fixed + (size_t)CH * 2048 * 5120 * 2 + 256 > ws_size) return;
  bf16* S_s = (bf16*)sub((size_t)CH * 2048 * 5120 * 2);

  // --- bf16 conversions ---
  to_bf16_k<<<2304, 256, 0, stream>>>((const float4*)x,      (bf16x4*)x_bf,     589824);
  to_bf16_k<<<1728, 256, 0, stream>>>((const float4*)w_qkv,  (bf16x4*)wqkv_bf,  442368);
  to_bf16_k<<< 768, 256, 0, stream>>>((const float4*)id_tot, (bf16x4*)id_bf,    196608);
  to_bf16_k<<< 585, 256, 0, stream>>>((const float4*)w_idkv, (bf16x4*)widkv_bf, 149760);
  to_bf16_k<<< 576, 256, 0, stream>>>((const float4*)w_proj, (bf16x4*)wproj_bf, 147456);

  // --- projections (no stats) ---
  gemm_nt<128,128,64,64,false,false,false><<<dim3(18, 24, 1), 256, 0, stream>>>(
      x_bf, wqkv_bf, qkv_f, nullptr, 3072, 2304, 768, 768, 768, 2304, 0, 0, 0,
      nullptr, nullptr, 0);
  gemm_nt<128,128,64,64,false,true,false><<<dim3(7, 8, 1), 256, 0, stream>>>(
      id_bf, widkv_bf, idkv_f, b_idkv, 1024, 780, 768, 768, 768, 780, 0, 0, 0,
      nullptr, nullptr, 0);

  // --- split + modulate + transposes ---
  split_qk_k<<<15360, 256, 0, stream>>>(qkv_f, idkv_f, mem_k, q_bf, kfull_bf, kmm_bf, out_kmm);
  build_vT_k<<<dim3(80, 12, 1), 256, 0, stream>>>(qkv_f, idkv_f, mem_v, vT_bf, out_vm);

  // --- memory-branch attention (L=1024) ---
  gemm_nt<128,128,64,64,true,false,true><<<dim3(8, 8, 12), 256, 0, stream>>>(
      q_bf, kmm_bf, S_m, nullptr, 1024, 1024, 64, 64, 64, 1024,
      (long)3072 * 64, (long)1024 * 64, (long)1024 * 1024, pss_m, psm_m, 16);
  finalize_stats_k<<<48, 256, 0, stream>>>(pss_m, psm_m, stats_m, 16, 1024, 1.0f / 1024.0f);
  av_fused<2><<<dim3(16, 12, 2), 256, 0, stream>>>(
      S_m, stats_m, vT_bf, av_part_m, psum_m, 1024, 1024, 2048, 0);

  // --- streaming-branch attention (L=5120), chunked over heads ---
  for (int h0 = 0; h0 < 12; h0 += CH) {
    gemm_nt<128,128,64,64,true,false,true><<<dim3(40, 16, CH), 256, 0, stream>>>(
        q_bf + (size_t)h0 * 3072 * 64 + 1024 * 64, kfull_bf + (size_t)h0 * 5120 * 64,
        S_s, nullptr, 2048, 5120, 64, 64, 64, 5120,
        (long)3072 * 64, (long)5120 * 64, (long)2048 * 5120, pss_s, psm_s, 80);
    finalize_stats_k<<<CH * 8, 256, 0, stream>>>(
        pss_s, psm_s, stats_s + (size_t)h0 * 2048, 80, 2048, 1.0f / 5120.0f);
    av_fused<8><<<dim3(32, CH, 8), 256, 0, stream>>>(
        S_s, stats_s, vT_bf, av_part_s, psum_s, 2048, 5120, 0, h0);
  }

  // --- reduce partials (normalize) + output projection ---
  reduce_cvt_k<<<2304, 256, 0, stream>>>((const float4*)av_part_m, (const float4*)av_part_s,
                                         (bf16x4*)xatt_bf, psum_m, psum_s);
  gemm_nt<128,128,64,64,false,false,false><<<dim3(6, 24, 1), 256, 0, stream>>>(
      xatt_bf, wproj_bf, out, b_proj, 3072, 768, 768, 768, 768, 768, 0, 0, 0,
      nullptr, nullptr, 0);
}

// Round 16
// 241.733 us; speedup vs baseline: 1.5565x; 1.3537x over previous
//
#include <hip/hip_runtime.h>
#include <hip/hip_bf16.h>

// ---------------------------------------------------------------------------
// Attention_32100585571137 : round 16 — S eliminated (2-pass flash)
//   pass 1: gemm_nt<CWRITE=false> = QK + mean/max stats, NO S write
//   pass 2: attn_fused = QK recompute -> exp -> PV, all in registers/LDS
//   P-fragment k-order absorbed into build_vT's global G-permutation
//   (same class of trick as r13's pi, which was verified bit-identical).
// ---------------------------------------------------------------------------

typedef __bf16 bf16;
typedef __attribute__((ext_vector_type(8))) __bf16 bf16x8;
typedef __attribute__((ext_vector_type(4))) __bf16 bf16x4;
typedef __attribute__((ext_vector_type(4))) float f32x4;

#define AS1 __attribute__((address_space(1)))
#define AS3 __attribute__((address_space(3)))

__device__ __forceinline__ void gll16(const void* g, void* l) {
  __builtin_amdgcn_global_load_lds((const AS1 void*)g, (AS3 void*)l, 16, 0, 0);
}

// ------------------------- f32 -> bf16 convert (x4) ------------------------
__global__ void to_bf16_k(const float4* __restrict__ s, bf16x4* __restrict__ d, int n4) {
  int i = blockIdx.x * 256 + threadIdx.x;
  if (i < n4) {
    float4 f = s[i];
    bf16x4 o;
    o[0] = (bf16)f.x; o[1] = (bf16)f.y; o[2] = (bf16)f.z; o[3] = (bf16)f.w;
    d[i] = o;
  }
}

// ------------------------- NT GEMM: C = A * B^T ----------------------------
// CWRITE=false: stats-only pass (no C store at all).
template<int BM, int BN, int WM, int WN, bool CBF16, bool NCLAMP, bool STATS, bool CWRITE>
__global__ __launch_bounds__(256, 2)
void gemm_nt(const bf16* __restrict__ A, const bf16* __restrict__ B,
             void* __restrict__ Cp, const float* __restrict__ bias,
             int M, int N, int K, int lda, int ldb, int ldc,
             long sA, long sB, long sC,
             float* __restrict__ pssum, unsigned* __restrict__ psmax, int slotsPerZ)
{
  constexpr int BK = 32;
  constexpr int MF = WM / 16, NF = WN / 16;
  constexpr int NWN = BN / WN;
  __shared__ __align__(16) bf16 As[BM * BK];
  __shared__ __align__(16) bf16 Bs[BN * BK];
  const int tid  = threadIdx.x;
  const int lane = tid & 63;
  const int wid  = tid >> 6;
  const int wm = (wid / NWN) * WM;
  const int wn = (wid % NWN) * WN;
  const int m0 = blockIdx.y * BM;
  const int n0 = blockIdx.x * BN;
  const bf16* Ab = A + (long)blockIdx.z * sA;
  const bf16* Bb = B + (long)blockIdx.z * sB;

  f32x4 acc[MF][NF] = {};
  const int wbase = wid << 10;
  const int aoffb = tid * 16;
  const int qs = ((lane >> 4) ^ ((lane >> 1) & 3)) * 8;

  for (int k0 = 0; k0 < K; k0 += BK) {
    #pragma unroll
    for (int i = 0; i < (BM * BK * 2) / 4096; ++i) {
      int off = i * 4096 + aoffb;
      int row = off >> 6;
      int q   = ((off >> 4) & 3) ^ ((off >> 7) & 3);
      const bf16* g = Ab + (long)(m0 + row) * lda + (k0 + q * 8);
      gll16(g, (char*)As + i * 4096 + wbase);
    }
    #pragma unroll
    for (int i = 0; i < (BN * BK * 2) / 4096; ++i) {
      int off = i * 4096 + aoffb;
      int row = off >> 6;
      int q   = ((off >> 4) & 3) ^ ((off >> 7) & 3);
      int rn = n0 + row;
      if (NCLAMP) rn = (rn < N) ? rn : (N - 1);
      const bf16* g = Bb + (long)rn * ldb + (k0 + q * 8);
      gll16(g, (char*)Bs + i * 4096 + wbase);
    }
    __syncthreads();
    bf16x8 af[MF], bfr[NF];
    #pragma unroll
    for (int i = 0; i < MF; ++i)
      af[i] = *reinterpret_cast<const bf16x8*>(&As[(wm + i * 16 + (lane & 15)) * BK + qs]);
    #pragma unroll
    for (int j = 0; j < NF; ++j)
      bfr[j] = *reinterpret_cast<const bf16x8*>(&Bs[(wn + j * 16 + (lane & 15)) * BK + qs]);
    #pragma unroll
    for (int i = 0; i < MF; ++i)
      #pragma unroll
      for (int j = 0; j < NF; ++j)
        acc[i][j] = __builtin_amdgcn_mfma_f32_16x16x32_bf16(bfr[j], af[i], acc[i][j], 0, 0, 0);
    __syncthreads();
  }

  if (CWRITE) {
    const long cbase = (long)blockIdx.z * sC;
    if (CBF16) {
      #pragma unroll
      for (int i = 0; i < MF; ++i) {
        const int r = m0 + wm + i * 16 + (lane & 15);
        #pragma unroll
        for (int jh = 0; jh < NF / 2; ++jh) {
          bf16x8 o;
          #pragma unroll
          for (int e = 0; e < 4; ++e) {
            o[e]     = (bf16)acc[i][2 * jh][e];
            o[4 + e] = (bf16)acc[i][2 * jh + 1][e];
          }
          const long idx = cbase + (long)r * ldc + n0 + wn + jh * 32 + ((lane >> 4) << 3);
          *reinterpret_cast<bf16x8*>((bf16*)Cp + idx) = o;
        }
      }
    } else {
      #pragma unroll
      for (int i = 0; i < MF; ++i) {
        const int r = m0 + wm + i * 16 + (lane & 15);
        #pragma unroll
        for (int j = 0; j < NF; ++j) {
          const int c = n0 + wn + j * 16 + ((lane >> 4) << 2);
          if (NCLAMP && c >= N) continue;
          float b0 = 0.0f, b1 = 0.0f, b2 = 0.0f, b3 = 0.0f;
          if (bias) {
            float4 bv = *reinterpret_cast<const float4*>(bias + c);
            b0 = bv.x; b1 = bv.y; b2 = bv.z; b3 = bv.w;
          }
          const long idx = cbase + (long)r * ldc + c;
          *reinterpret_cast<float4*>((float*)Cp + idx) =
              make_float4(acc[i][j][0] + b0, acc[i][j][1] + b1,
                          acc[i][j][2] + b2, acc[i][j][3] + b3);
        }
      }
    }
  }

  if (STATS) {
    const long sbase = ((long)blockIdx.z * slotsPerZ + blockIdx.x * NWN + (wid % NWN)) * M;
    #pragma unroll
    for (int i = 0; i < MF; ++i) {
      float s = 0.0f, mxv = -3.0e38f;
      #pragma unroll
      for (int j = 0; j < NF; ++j)
        #pragma unroll
        for (int rr = 0; rr < 4; ++rr) {
          s += acc[i][j][rr];
          mxv = fmaxf(mxv, acc[i][j][rr]);
        }
      s += __shfl_xor(s, 16, 64);
      s += __shfl_xor(s, 32, 64);
      mxv = fmaxf(mxv, __shfl_xor(mxv, 16, 64));
      mxv = fmaxf(mxv, __shfl_xor(mxv, 32, 64));
      if (lane < 16) {
        const int grow = m0 + wm + i * 16 + lane;
        pssum[sbase + grow] = s;
        unsigned u = __float_as_uint(mxv);
        psmax[sbase + grow] = u ^ (((int)u >> 31) ? 0xFFFFFFFFu : 0x80000000u);
      }
    }
  }
}

// --------------- finalize stats: reduce slots -> (mean, max) ---------------
__global__ void finalize_stats_k(const float* __restrict__ pssum,
                                 const unsigned* __restrict__ psmax,
                                 float4* __restrict__ st,
                                 int nslots, int Mrows, float invL)
{
  const int idx = blockIdx.x * 256 + threadIdx.x;
  const int z = idx / Mrows, r = idx - z * Mrows;
  const float*    ps = pssum + (long)z * nslots * Mrows + r;
  const unsigned* pm = psmax + (long)z * nslots * Mrows + r;
  float s = 0.0f;
  unsigned km = 0;
  for (int i = 0; i < nslots; ++i) {
    s += ps[(long)i * Mrows];
    km = max(km, pm[(long)i * Mrows]);
  }
  unsigned ub = (km & 0x80000000u) ? (km ^ 0x80000000u) : ~km;
  st[idx] = make_float4(s * invL, __uint_as_float(ub), 0.0f, 0.0f);
}

// --------------- split qkv -> q(scaled), k_full, k_m_mod -------------------
__global__ void split_qk_k(const float* __restrict__ qkv, const float* __restrict__ idkv,
                           const float* __restrict__ mem_k,
                           bf16* __restrict__ q_bf, bf16* __restrict__ kfull,
                           bf16* __restrict__ kmm, float* __restrict__ out_kmm)
{
  int idx = blockIdx.x * 256 + threadIdx.x;
  if (idx >= 12 * 5120 * 64) return;
  int d  = idx & 63;
  int hj = idx >> 6;
  int h  = hj / 5120;
  int j  = hj - h * 5120;
  if (j < 2048) {
    kfull[idx] = (bf16)mem_k[((h * 2048 + j) << 6) + d];
  } else {
    int n = j - 2048;
    int base = n * 2304 + (h << 6) + d;
    float qv = qkv[base];
    float kv = qkv[base + 768];
    q_bf[((h * 3072 + n) << 6) + d] = (bf16)(qv * 0.125f);
    kfull[idx] = (bf16)kv;
    if (n < 1024) {
      float m  = 1.0f + tanhf(idkv[n * 780 + h]);
      float km = kv * m;
      int o = ((h * 1024 + n) << 6) + d;
      kmm[o]     = (bf16)km;
      out_kmm[o] = km;
    }
  }
}

// --------------- build v^T (64 x 5120 per head), G-permuted k-index --------
// G(P): s=P>>3, e=P&7, c=s>>2, g=s&3 -> col=(2c+(e>>2))*16+g*4+(e&3)
// inverse: jj -> P = ((c*4+g)<<3) + half*4 + r  (c=jpair>>1, half=jpair&1)
__global__ void build_vT_k(const float* __restrict__ qkv, const float* __restrict__ idkv,
                           const float* __restrict__ mem_v,
                           bf16* __restrict__ vT, float* __restrict__ out_vm)
{
  __shared__ float tile[64][65];
  int h  = blockIdx.y;
  int j0 = blockIdx.x << 6;
  int tid = threadIdx.x;
  #pragma unroll
  for (int i = 0; i < 16; ++i) {
    int el = i * 256 + tid;
    int jj = el >> 6, d = el & 63;
    int j = j0 + jj;
    float v;
    if (j < 2048) {
      v = mem_v[((h * 2048 + j) << 6) + d];
    } else {
      int n = j - 2048;
      v = qkv[n * 2304 + 1536 + (h << 6) + d];
      if (n < 1024) {
        v += idkv[n * 780 + 12 + (h << 6) + d];
        out_vm[((h * 1024 + n) << 6) + d] = v;
      }
    }
    tile[jj][d] = v;
  }
  __syncthreads();
  #pragma unroll
  for (int i = 0; i < 16; ++i) {
    int el = i * 256 + tid;
    int d = el >> 6, jj = el & 63;
    int jpair = jj >> 4, rem = jj & 15;
    int g = rem >> 2, r = rem & 3;
    int c = jpair >> 1, half = jpair & 1;
    int P = ((c * 4 + g) << 3) + half * 4 + r;
    vT[((long)(h * 64 + d)) * 5120 + j0 + P] = (bf16)tile[jj][d];
  }
}

// --------------- fused attention pass 2: QK -> exp -> PV, no S -------------
// block: 128 q-rows (4 waves x 32) x d=64, over one k-chunk. K,V staged in
// dbuf LDS (slot ^= row&7 swizzle, linear gll16 dest + swizzled source).
// Q fragments in registers. P never leaves registers; its fragment k-order
// matches V's G-permuted global layout.
template<int KSPLIT>
__global__ __launch_bounds__(256)
void attn_fused(const bf16* __restrict__ Q, const bf16* __restrict__ Kb,
                const bf16* __restrict__ Vg, const float4* __restrict__ st,
                float* __restrict__ part, float* __restrict__ psum,
                int M, int L, int qOff, int vOff, long sQ, long sK, int Lv)
{
  __shared__ __align__(16) bf16 kbuf[2][64 * 64];
  __shared__ __align__(16) bf16 vbuf[2][64 * 64];
  const int tid = threadIdx.x, lane = tid & 63, w = tid >> 6, g = lane >> 4;
  const int h = blockIdx.y;
  const int q0 = blockIdx.x * 128 + w * 32;
  const int kchunk = L / KSPLIT;
  const int kbase = blockIdx.z * kchunk;
  const int nst = kchunk / 64;

  // Q fragments (held whole kernel): qf[i][dstep]
  bf16x8 qf[2][2];
  float t[2], mx[2];
  #pragma unroll
  for (int i = 0; i < 2; ++i) {
    const long qrow = qOff + q0 + i * 16 + (lane & 15);
    #pragma unroll
    for (int ds = 0; ds < 2; ++ds)
      qf[i][ds] = *reinterpret_cast<const bf16x8*>(Q + (long)h * sQ + qrow * 64 + ds * 32 + g * 8);
    float4 s4 = st[h * M + q0 + i * 16 + (lane & 15)];
    t[i] = s4.x; mx[i] = s4.y;
  }

  // staging geometry: round R covers LDS rows R*32 + (tid>>3), slotL = tid&7
  const int srow = tid >> 3;
  const int slotL = tid & 7;
  const bf16* ksrc0 = Kb + (long)h * sK + (long)(kbase + srow) * 64 + ((slotL ^ (srow & 7)) * 8);
  const bf16* ksrc1 = Kb + (long)h * sK + (long)(kbase + 32 + srow) * 64 + ((slotL ^ ((srow + 32) & 7)) * 8);
  const bf16* vsrc0 = Vg + ((long)h * 64 + srow) * Lv + vOff + kbase + ((slotL ^ (srow & 7)) * 8);
  const bf16* vsrc1 = Vg + ((long)h * 64 + 32 + srow) * Lv + vOff + kbase + ((slotL ^ ((srow + 32) & 7)) * 8);

  f32x4 oacc[2][4] = {};
  float lsum[2] = {0.0f, 0.0f};

  gll16(ksrc0, (char*)kbuf[0] + tid * 16);
  gll16(ksrc1, (char*)kbuf[0] + 4096 + tid * 16);
  gll16(vsrc0, (char*)vbuf[0] + tid * 16);
  gll16(vsrc1, (char*)vbuf[0] + 4096 + tid * 16);
  __syncthreads();

  for (int s = 0; s < nst; ++s) {
    const int b = s & 1;
    if (s + 1 < nst) {
      const int nb = b ^ 1;
      gll16(ksrc0 + (long)(s + 1) * 4096, (char*)kbuf[nb] + tid * 16);
      gll16(ksrc1 + (long)(s + 1) * 4096, (char*)kbuf[nb] + 4096 + tid * 16);
      gll16(vsrc0 + (s + 1) * 64, (char*)vbuf[nb] + tid * 16);
      gll16(vsrc1 + (s + 1) * 64, (char*)vbuf[nb] + 4096 + tid * 16);
    }

    // QK: sacc[i][j] over 64-col tile
    f32x4 sacc[2][4] = {};
    const char* kb = (const char*)kbuf[b];
    #pragma unroll
    for (int ds = 0; ds < 2; ++ds) {
      bf16x8 kf[4];
      #pragma unroll
      for (int j = 0; j < 4; ++j) {
        const int row = j * 16 + (lane & 15);
        kf[j] = *reinterpret_cast<const bf16x8*>(kb + row * 128 + (((ds * 4 + g) ^ (row & 7)) << 4));
      }
      #pragma unroll
      for (int i = 0; i < 2; ++i)
        #pragma unroll
        for (int j = 0; j < 4; ++j)
          sacc[i][j] = __builtin_amdgcn_mfma_f32_16x16x32_bf16(kf[j], qf[i][ds], sacc[i][j], 0, 0, 0);
    }

    // exp + sum (threshold/max per row i)
    #pragma unroll
    for (int i = 0; i < 2; ++i)
      #pragma unroll
      for (int j = 0; j < 4; ++j)
        #pragma unroll
        for (int r = 0; r < 4; ++r) {
          float v = sacc[i][j][r];
          float p = (v >= t[i]) ? __expf(v - mx[i]) : 0.0f;
          sacc[i][j][r] = p;
          lsum[i] += p;
        }

    // PV: pack P frags as A-operands; V read in G-matched slots
    const char* vb = (const char*)vbuf[b];
    #pragma unroll
    for (int c = 0; c < 2; ++c) {
      bf16x8 pa[2];
      #pragma unroll
      for (int i = 0; i < 2; ++i) {
        bf16x8 p8;
        #pragma unroll
        for (int e = 0; e < 4; ++e) {
          p8[e]     = (bf16)sacc[i][2 * c][e];
          p8[4 + e] = (bf16)sacc[i][2 * c + 1][e];
        }
        pa[i] = p8;
      }
      #pragma unroll
      for (int f = 0; f < 4; ++f) {
        const int row = f * 16 + (lane & 15);
        bf16x8 vf = *reinterpret_cast<const bf16x8*>(vb + row * 128 + (((c * 4 + g) ^ (row & 7)) << 4));
        #pragma unroll
        for (int i = 0; i < 2; ++i)
          oacc[i][f] = __builtin_amdgcn_mfma_f32_16x16x32_bf16(vf, pa[i], oacc[i][f], 0, 0, 0);
      }
    }
    __syncthreads();
  }

  // per-row denominator partials: lanes {r, r+16, r+32, r+48} share row r
  #pragma unroll
  for (int i = 0; i < 2; ++i) {
    float s = lsum[i];
    s += __shfl_down(s, 32, 64);
    s += __shfl_down(s, 16, 64);
    if (g == 0)
      psum[((long)blockIdx.z * 12 + h) * M + q0 + i * 16 + (lane & 15)] = s;
  }

  float* pp = part + (long)blockIdx.z * M * 768;
  #pragma unroll
  for (int i = 0; i < 2; ++i) {
    const long row = q0 + i * 16 + (lane & 15);
    #pragma unroll
    for (int f = 0; f < 4; ++f) {
      const int cc = h * 64 + f * 16 + g * 4;
      *reinterpret_cast<float4*>(pp + row * 768 + cc) =
          make_float4(oacc[i][f][0], oacc[i][f][1], oacc[i][f][2], oacc[i][f][3]);
    }
  }
}

// --------------- reduce split-K partials, normalize, cvt bf16 --------------
__global__ void reduce_cvt_k(const float4* __restrict__ part_m, const float4* __restrict__ part_s,
                             bf16x4* __restrict__ xatt,
                             const float* __restrict__ psum_m, const float* __restrict__ psum_s)
{
  const int idx = blockIdx.x * 256 + threadIdx.x;
  if (idx >= 589824) return;
  const int row = idx / 192;
  const int c4 = idx - row * 192;
  const int h = (c4 * 4) >> 6;
  float sx = 0.0f, sy = 0.0f, sz = 0.0f, sw = 0.0f, sum = 0.0f;
  if (row < 1024) {
    constexpr long P4 = (long)1024 * 192;
    #pragma unroll
    for (int z = 0; z < 4; ++z) {
      float4 a = part_m[(long)z * P4 + (long)row * 192 + c4];
      sx += a.x; sy += a.y; sz += a.z; sw += a.w;
      sum += psum_m[((long)z * 12 + h) * 1024 + row];
    }
  } else {
    const int r = row - 1024;
    constexpr long P4 = (long)2048 * 192;
    #pragma unroll
    for (int z = 0; z < 4; ++z) {
      float4 a = part_s[(long)z * P4 + (long)r * 192 + c4];
      sx += a.x; sy += a.y; sz += a.z; sw += a.w;
      sum += psum_s[((long)z * 12 + h) * 2048 + r];
    }
  }
  const float inv = 1.0f / sum;
  bf16x4 o;
  o[0] = (bf16)(sx * inv); o[1] = (bf16)(sy * inv);
  o[2] = (bf16)(sz * inv); o[3] = (bf16)(sw * inv);
  xatt[idx] = o;
}

// ---------------------------------------------------------------------------
extern "C" void kernel_launch(void* const* d_in, const int* in_sizes, int n_in,
                              void* d_out, int out_size, void* d_ws, size_t ws_size,
                              hipStream_t stream)
{
  (void)in_sizes; (void)n_in; (void)out_size; (void)ws_size;
  const float* x      = (const float*)d_in[0];
  const float* id_tot = (const float*)d_in[1];
  const float* mem_k  = (const float*)d_in[2];
  const float* mem_v  = (const float*)d_in[3];
  const float* w_qkv  = (const float*)d_in[4];
  const float* w_idkv = (const float*)d_in[5];
  const float* b_idkv = (const float*)d_in[6];
  const float* w_proj = (const float*)d_in[7];
  const float* b_proj = (const float*)d_in[8];

  float* out     = (float*)d_out;
  float* out_kmm = out + (size_t)3072 * 768;
  float* out_vm  = out_kmm + (size_t)12 * 1024 * 64;

  char* cur = (char*)d_ws;
  auto sub = [&](size_t b) { char* p = cur; cur += (b + 255) & ~(size_t)255; return p; };

  // ---- union region: early temps (dead after split/build) vs av_part_s ----
  char* uni0 = cur;
  bf16*  x_bf     = (bf16*) sub((size_t)3072 * 768 * 2);
  bf16*  wqkv_bf  = (bf16*) sub((size_t)2304 * 768 * 2);
  bf16*  id_bf    = (bf16*) sub((size_t)1024 * 768 * 2);
  bf16*  widkv_bf = (bf16*) sub((size_t)780 * 768 * 2);
  float* qkv_f    = (float*)sub((size_t)3072 * 2304 * 4);
  float* idkv_f   = (float*)sub((size_t)1024 * 780 * 4);
  char* uniEndA = cur;
  float* av_part_s = (float*)uni0;                      // 4 * 2048*768 f32
  char* uniEndB = uni0 + (size_t)4 * 2048 * 768 * 4;
  cur = (uniEndA > uniEndB) ? uniEndA : uniEndB;

  // ---- persistent ----
  bf16*     wproj_bf  = (bf16*)    sub((size_t)768 * 768 * 2);
  bf16*     q_bf      = (bf16*)    sub((size_t)12 * 3072 * 64 * 2);
  bf16*     kfull_bf  = (bf16*)    sub((size_t)12 * 5120 * 64 * 2);
  bf16*     vT_bf     = (bf16*)    sub((size_t)12 * 64 * 5120 * 2);
  bf16*     kmm_bf    = (bf16*)    sub((size_t)12 * 1024 * 64 * 2);
  float*    av_part_m = (float*)   sub((size_t)4 * 1024 * 768 * 4);
  float4*   stats_m   = (float4*)  sub((size_t)12 * 1024 * 16);
  float4*   stats_s   = (float4*)  sub((size_t)12 * 2048 * 16);
  float*    psum_m    = (float*)   sub((size_t)4 * 12 * 1024 * 4);
  float*    psum_s    = (float*)   sub((size_t)4 * 12 * 2048 * 4);
  float*    pss_m     = (float*)   sub((size_t)12 * 16 * 1024 * 4);
  unsigned* psm_m     = (unsigned*)sub((size_t)12 * 16 * 1024 * 4);
  float*    pss_s     = (float*)   sub((size_t)12 * 80 * 2048 * 4);
  unsigned* psm_s     = (unsigned*)sub((size_t)12 * 80 * 2048 * 4);
  bf16*     xatt_bf   = (bf16*)    sub((size_t)3072 * 768 * 2);

  // --- bf16 conversions ---
  to_bf16_k<<<2304, 256, 0, stream>>>((const float4*)x,      (bf16x4*)x_bf,     589824);
  to_bf16_k<<<1728, 256, 0, stream>>>((const float4*)w_qkv,  (bf16x4*)wqkv_bf,  442368);
  to_bf16_k<<< 768, 256, 0, stream>>>((const float4*)id_tot, (bf16x4*)id_bf,    196608);
  to_bf16_k<<< 585, 256, 0, stream>>>((const float4*)w_idkv, (bf16x4*)widkv_bf, 149760);
  to_bf16_k<<< 576, 256, 0, stream>>>((const float4*)w_proj, (bf16x4*)wproj_bf, 147456);

  // --- projections ---
  gemm_nt<128,128,64,64,false,false,false,true><<<dim3(18, 24, 1), 256, 0, stream>>>(
      x_bf, wqkv_bf, qkv_f, nullptr, 3072, 2304, 768, 768, 768, 2304, 0, 0, 0,
      nullptr, nullptr, 0);
  gemm_nt<128,128,64,64,false,true,false,true><<<dim3(7, 8, 1), 256, 0, stream>>>(
      id_bf, widkv_bf, idkv_f, b_idkv, 1024, 780, 768, 768, 768, 780, 0, 0, 0,
      nullptr, nullptr, 0);

  // --- split + modulate + transposes ---
  split_qk_k<<<15360, 256, 0, stream>>>(qkv_f, idkv_f, mem_k, q_bf, kfull_bf, kmm_bf, out_kmm);
  build_vT_k<<<dim3(80, 12, 1), 256, 0, stream>>>(qkv_f, idkv_f, mem_v, vT_bf, out_vm);

  // --- memory branch: stats pass (no S write) + fused attention ---
  gemm_nt<128,128,64,64,true,false,true,false><<<dim3(8, 8, 12), 256, 0, stream>>>(
      q_bf, kmm_bf, nullptr, nullptr, 1024, 1024, 64, 64, 64, 1024,
      (long)3072 * 64, (long)1024 * 64, 0, pss_m, psm_m, 16);
  finalize_stats_k<<<48, 256, 0, stream>>>(pss_m, psm_m, stats_m, 16, 1024, 1.0f / 1024.0f);
  attn_fused<4><<<dim3(8, 12, 4), 256, 0, stream>>>(
      q_bf, kmm_bf, vT_bf, stats_m, av_part_m, psum_m,
      1024, 1024, 0, 2048, (long)3072 * 64, (long)1024 * 64, 5120);

  // --- streaming branch: stats pass + fused attention (single dispatch) ---
  gemm_nt<128,128,64,64,true,false,true,false><<<dim3(40, 16, 12), 256, 0, stream>>>(
      q_bf + (size_t)1024 * 64, kfull_bf, nullptr, nullptr, 2048, 5120, 64, 64, 64, 5120,
      (long)3072 * 64, (long)5120 * 64, 0, pss_s, psm_s, 80);
  finalize_stats_k<<<96, 256, 0, stream>>>(pss_s, psm_s, stats_s, 80, 2048, 1.0f / 5120.0f);
  attn_fused<4><<<dim3(16, 12, 4), 256, 0, stream>>>(
      q_bf, kfull_bf, vT_bf, stats_s, av_part_s, psum_s,
      2048, 5120, 1024, 0, (long)3072 * 64, (long)5120 * 64, 5120);

  // --- reduce partials (normalize) + output projection ---
  reduce_cvt_k<<<2304, 256, 0, stream>>>((const float4*)av_part_m, (const float4*)av_part_s,
                                         (bf16x4*)xatt_bf, psum_m, psum_s);
  gemm_nt<128,128,64,64,false,false,false,true><<<dim3(6, 24, 1), 256, 0, stream>>>(
      xatt_bf, wproj_bf, out, b_proj, 3072, 768, 768, 768, 768, 768, 0, 0, 0,
      nullptr, nullptr, 0);
}